// Round 1
// baseline (3641.025 us; speedup 1.0000x reference)
//
#include <hip/hip_runtime.h>
#include <stdint.h>

// Problem constants
#define NB 8
#define NPT 8192
#define ND 64
#define NO 128
#define NS 2048
#define NK 16

// Workspace layout (in floats)
constexpr int WS_PTS_T  = 0;                         // [B][N][64] transposed points
constexpr int WS_XYZW   = WS_PTS_T + NB*NPT*ND;      // [B][N][4] x,y,z,|p|^2
constexpr int WS_NEWXYZ = WS_XYZW + NB*NPT*4;        // [B][S][4] x,y,z,|q|^2
constexpr int WS_KNN    = WS_NEWXYZ + NB*NS*4;       // [B][S][16] int
constexpr int WS_AGG    = WS_KNN + NB*NS*NK;         // [B][S][144]
constexpr int WS_GATES  = WS_AGG + NB*NS*144;        // [B][S][144] (wc 0..127, wp 128..143)

// Output layout (floats): new_xyz [B][3][S], out [B][O][S], fps_idx [B][S]
constexpr int OUT_NEWXYZ = 0;
constexpr int OUT_FEAT   = NB*3*NS;
constexpr int OUT_FPS    = OUT_FEAT + NB*NO*NS;

__device__ __forceinline__ float sq3(float x, float y, float z) {
#pragma clang fp contract(off)
  return (x*x + y*y) + z*z;
}

__device__ __forceinline__ float fps_d(float px,float py,float pz,float cx,float cy,float cz) {
#pragma clang fp contract(off)
  float dx = px-cx, dy = py-cy, dz = pz-cz;
  return (dx*dx + dy*dy) + dz*dz;
}

__device__ __forceinline__ float knn_d(float qn, float pn,
                                       float qx,float qy,float qz,
                                       float px,float py,float pz) {
#pragma clang fp contract(off)
  float dot = (qx*px + qy*py) + qz*pz;
  return (qn + pn) - 2.0f*dot;
}

// ---------------- Kernel 1: fused FPS (blocks 0..7) + points transpose + xyzw build ----
struct FpsShared {
  float lx[NPT], ly[NPT], lz[NPT];
  unsigned long long wred[2][16];
};
struct TrShared { float tile[64][65]; };
union PrepShared { FpsShared f; TrShared t; };

__global__ __launch_bounds__(1024) void k_prep(const float* __restrict__ xyz,
                                               const float* __restrict__ points,
                                               float* __restrict__ ws,
                                               float* __restrict__ dout) {
  __shared__ PrepShared sh;
  const int bid = blockIdx.x, t = threadIdx.x;

  if (bid < NB) {
    // ---- FPS for batch bid (exact replication of reference arithmetic) ----
    const float* xb = xyz + (size_t)bid*3*NPT;
    float px[8], py[8], pz[8], dist[8];
#pragma unroll
    for (int j = 0; j < 8; j++) {
      int n = t + j*1024;
      float x = xb[n], y = xb[NPT+n], z = xb[2*NPT+n];
      px[j]=x; py[j]=y; pz[j]=z; dist[j]=1e10f;
      sh.f.lx[n]=x; sh.f.ly[n]=y; sh.f.lz[n]=z;
    }
    __syncthreads();

    int far = 0;
    float* nxw  = ws + WS_NEWXYZ + (size_t)bid*NS*4;
    float* nxo  = dout + OUT_NEWXYZ + (size_t)bid*3*NS;
    float* fpso = dout + OUT_FPS + (size_t)bid*NS;

    for (int s = 0; s < NS; s++) {
      float cx = sh.f.lx[far], cy = sh.f.ly[far], cz = sh.f.lz[far];
      if (t == 0) {
        fpso[s] = (float)far;
        nxo[s] = cx; nxo[NS+s] = cy; nxo[2*NS+s] = cz;
        float cw = sq3(cx, cy, cz);
        nxw[s*4+0]=cx; nxw[s*4+1]=cy; nxw[s*4+2]=cz; nxw[s*4+3]=cw;
      }
      // update running min distance + local argmax (first-index tie-break: ascending scan, strict >)
      float bv = -1.0f; int bi = 0;
#pragma unroll
      for (int j = 0; j < 8; j++) {
        float d = fps_d(px[j], py[j], pz[j], cx, cy, cz);
        float nd = fminf(dist[j], d);
        dist[j] = nd;
        if (nd > bv) { bv = nd; bi = t + j*1024; }
      }
      // pack: max by value, ties -> min index  (dist >= 0 so raw float bits are order-preserving)
      unsigned long long key = ((unsigned long long)__float_as_uint(bv) << 32)
                             | (unsigned)(8191 - bi);
#pragma unroll
      for (int m = 1; m < 64; m <<= 1) {
        unsigned long long o = __shfl_xor(key, m, 64);
        key = (o > key) ? o : key;
      }
      const int par = s & 1;
      if ((t & 63) == 0) sh.f.wred[par][t >> 6] = key;
      __syncthreads();
      key = sh.f.wred[par][t & 15];
#pragma unroll
      for (int m = 1; m < 16; m <<= 1) {
        unsigned long long o = __shfl_xor(key, m, 16);
        key = (o > key) ? o : key;
      }
      far = 8191 - (int)(key & 0xFFFFFFFFull);
    }
  } else if (bid < NB + 1024) {
    // ---- transpose points [B][64][N] -> pts_t [B][N][64] ----
    const int tb = bid - NB;
    const int b  = tb >> 7;            // 128 n-tiles per batch
    const int n0 = (tb & 127) << 6;
    const float* pb = points + (size_t)b*ND*NPT;
    {
      int dR = t >> 4, cg = t & 15;
      float4 v = *reinterpret_cast<const float4*>(pb + (size_t)dR*NPT + n0 + cg*4);
      sh.t.tile[dR][cg*4+0]=v.x; sh.t.tile[dR][cg*4+1]=v.y;
      sh.t.tile[dR][cg*4+2]=v.z; sh.t.tile[dR][cg*4+3]=v.w;
    }
    __syncthreads();
    {
      int nl = t >> 4, dg = t & 15;
      float4 v;
      v.x = sh.t.tile[dg*4+0][nl]; v.y = sh.t.tile[dg*4+1][nl];
      v.z = sh.t.tile[dg*4+2][nl]; v.w = sh.t.tile[dg*4+3][nl];
      *reinterpret_cast<float4*>(ws + WS_PTS_T + ((size_t)b*NPT + n0 + nl)*ND + dg*4) = v;
    }
  } else {
    // ---- xyzw build: [B][N][4] = x,y,z,|p|^2 ----
    int g = (bid - (NB + 1024))*1024 + t;      // 64 blocks * 1024 = B*N
    int b = g >> 13, n = g & 8191;
    const float* xb = xyz + (size_t)b*3*NPT;
    float x = xb[n], y = xb[NPT+n], z = xb[2*NPT+n];
    float4 v; v.x=x; v.y=y; v.z=z; v.w=sq3(x,y,z);
    *reinterpret_cast<float4*>(ws + WS_XYZW + (size_t)g*4) = v;
  }
}

// ---------------- Kernel 2: KNN + feat pass 1 (ch_avg / pt_avg -> agg) --------------
struct K2Shared {
  union {
    float dist[NPT];                       // 32 KB (phase A/B)
    struct {
      float W[128*69];                     // W_kernel staged, row stride 69 (odd->conflict-free)
      float np[16*69];                     // grouped features [k][67]
      float ft[16*132];                    // feat tile [k][o]
      float chred[256];
      float ptred[16*17];
    } p2;
  } u;
  unsigned long long kred[4];
  int selIdx[16];
};

__global__ __launch_bounds__(256) void k_knn_feat1(const float* __restrict__ Wkern,
                                                   float* __restrict__ ws) {
  __shared__ K2Shared sh;
  const int bid = blockIdx.x, t = threadIdx.x;
  const int b = bid >> 11, s = bid & 2047;
  const float* xyzw = ws + WS_XYZW + (size_t)b*NPT*4;
  const float4 q = *reinterpret_cast<const float4*>(ws + WS_NEWXYZ + ((size_t)b*NS + s)*4);

  // phase A: full distance row into LDS
  for (int i = 0; i < 32; i++) {
    int n = t + (i << 8);
    float4 p = *reinterpret_cast<const float4*>(xyzw + (size_t)n*4);
    sh.u.dist[n] = knn_d(q.w, p.w, q.x, q.y, q.z, p.x, p.y, p.z);
  }
  __syncthreads();

  // phase B: 16 x (argmin + mark) == stable top-16 (ties -> lower index)
  int* knn = (int*)(ws + WS_KNN) + ((size_t)b*NS + s)*NK;
  for (int r = 0; r < NK; r++) {
    float bv = __int_as_float(0x7F800000); int bi = NPT;
    for (int i = 0; i < 32; i++) {
      int n = t + (i << 8);
      float v = sh.u.dist[n];
      if (v < bv) { bv = v; bi = n; }
    }
    unsigned u = __float_as_uint(bv);
    u ^= ((unsigned)((int)u >> 31)) | 0x80000000u;   // order-preserving map (handles negatives)
    unsigned long long key = ((unsigned long long)u << 32) | (unsigned)bi;
#pragma unroll
    for (int m = 1; m < 64; m <<= 1) {
      unsigned long long o = __shfl_xor(key, m, 64);
      key = (o < key) ? o : key;
    }
    if ((t & 63) == 0) sh.kred[t >> 6] = key;
    __syncthreads();
    {
      unsigned long long kmin = sh.kred[0];
#pragma unroll
      for (int w = 1; w < 4; w++) { unsigned long long o = sh.kred[w]; kmin = (o < kmin) ? o : kmin; }
      int win = (int)(kmin & 0xFFFFFFFFull);
      if (t == 0) { sh.selIdx[r] = win; knn[r] = win; sh.u.dist[win] = __int_as_float(0x7F800000); }
    }
    __syncthreads();
  }

  // phase C: gather grouped features into LDS (np[k][0..2]=gxyz-q, [3..66]=pts_t row)
  {
    int k = t >> 4, cg = t & 15;
    int idx = sh.selIdx[k];
    float4 f = *reinterpret_cast<const float4*>(ws + WS_PTS_T + ((size_t)b*NPT + idx)*ND + cg*4);
    float* nprow = sh.u.p2.np + k*69;
    nprow[3+cg*4+0]=f.x; nprow[3+cg*4+1]=f.y; nprow[3+cg*4+2]=f.z; nprow[3+cg*4+3]=f.w;
    if (cg == 0) {
      float4 g4 = *reinterpret_cast<const float4*>(xyzw + (size_t)idx*4);
      nprow[0]=g4.x-q.x; nprow[1]=g4.y-q.y; nprow[2]=g4.z-q.z;
    }
  }
  // stage W_kernel
  for (int g = t; g < 128*67; g += 256) {
    int o = g / 67, c = g - o*67;
    sh.u.p2.W[o*69+c] = Wkern[g];
  }
  __syncthreads();

  // phase E: feat[o][k] = leaky(W . np)
  const int o = t & 127, khalf = t >> 7, k0 = khalf*8;
  float acc[8] = {0,0,0,0,0,0,0,0};
  const float* Wrow = sh.u.p2.W + o*69;
  for (int c = 0; c < 67; c++) {
    float w = Wrow[c];
#pragma unroll
    for (int kk = 0; kk < 8; kk++)
      acc[kk] = fmaf(w, sh.u.p2.np[(k0+kk)*69 + c], acc[kk]);
  }
#pragma unroll
  for (int kk = 0; kk < 8; kk++) { float a = acc[kk]; acc[kk] = (a >= 0.f) ? a : 0.1f*a; }

  // phase F: ch_avg + pt_avg -> agg[b][s][144]
  float chp = 0.f;
#pragma unroll
  for (int kk = 0; kk < 8; kk++) { sh.u.p2.ft[(k0+kk)*132 + o] = acc[kk]; chp += acc[kk]; }
  sh.u.p2.chred[khalf*128 + o] = chp;
  __syncthreads();
  float* agg = ws + WS_AGG + ((size_t)b*NS + s)*144;
  if (t < 128) agg[t] = (sh.u.p2.chred[t] + sh.u.p2.chred[128+t]) * 0.0625f;
  {
    int k = t & 15, og = t >> 4;
    float pp = 0.f;
#pragma unroll
    for (int j = 0; j < 8; j++) pp += sh.u.p2.ft[k*132 + og*8 + j];
    sh.u.p2.ptred[k*17 + og] = pp;
  }
  __syncthreads();
  if (t < 16) {
    float pv = 0.f;
#pragma unroll
    for (int og = 0; og < 16; og++) pv += sh.u.p2.ptred[t*17 + og];
    agg[128 + t] = pv * 0.0078125f;
  }
}

// ---------------- Kernel 3: linear + gates ----------------
struct K3Shared {
  float Wlin[144*145];
  float Wch[128*129];
  float Wpt[16*17];
  float av[144];
  float a2[144];
};

__global__ __launch_bounds__(256) void k_linear(const float* __restrict__ Wlin,
                                                const float* __restrict__ Wpt,
                                                const float* __restrict__ Wch,
                                                float* __restrict__ ws) {
  __shared__ K3Shared sh;
  const int t = threadIdx.x, bid = blockIdx.x;
  for (int g = t; g < 144*144; g += 256) { int o = g/144, c = g - o*144; sh.Wlin[o*145+c] = Wlin[g]; }
  for (int g = t; g < 128*128; g += 256) { int o = g>>7, c = g&127;      sh.Wch[o*129+c]  = Wch[g]; }
  if (t < 256) { int o = t>>4, c = t&15; sh.Wpt[o*17+c] = Wpt[t]; }
  __syncthreads();

  for (int i = 0; i < 8; i++) {
    const size_t sg = (size_t)bid*8 + i;
    const float* agg = ws + WS_AGG + sg*144;
    if (t < 144) sh.av[t] = agg[t];
    __syncthreads();
    if (t < 144) {
      float a = 0.f;
      const float* wr = sh.Wlin + t*145;
      for (int c = 0; c < 144; c++) a = fmaf(wr[c], sh.av[c], a);
      sh.a2[t] = (a >= 0.f) ? a : 0.1f*a;
    }
    __syncthreads();
    float* gates = ws + WS_GATES + sg*144;
    if (t < 128) {
      float a = 0.f;
      const float* wr = sh.Wch + t*129;
      for (int c = 0; c < 128; c++) a = fmaf(wr[c], sh.a2[c], a);
      gates[t] = 1.f / (1.f + expf(-a));
    } else if (t < 144) {
      int o = t - 128;
      float a = 0.f;
      const float* wr = sh.Wpt + o*17;
      for (int c = 0; c < 16; c++) a = fmaf(wr[c], sh.a2[128+c], a);
      gates[t] = 1.f / (1.f + expf(-a));
    }
    __syncthreads();
  }
}

// ---------------- Kernel 4: recompute feat, gate, mean over k -> out ----------------
struct K4Shared {
  float W[128*69];
  float np[16*69];
  float pr[256];
  float g[144];
  int sel[16];
};

__global__ __launch_bounds__(256) void k_final(const float* __restrict__ Wkern,
                                               const float* __restrict__ ws,
                                               float* __restrict__ dout) {
  __shared__ K4Shared sh;
  const int bid = blockIdx.x, t = threadIdx.x;
  const int b = bid >> 11, s = bid & 2047;
  const int* knn = (const int*)(ws + WS_KNN) + ((size_t)b*NS + s)*NK;
  if (t < 16)  sh.sel[t] = knn[t];
  if (t < 144) sh.g[t] = ws[WS_GATES + ((size_t)b*NS + s)*144 + t];
  const float4 q = *reinterpret_cast<const float4*>(ws + WS_NEWXYZ + ((size_t)b*NS + s)*4);
  for (int gg = t; gg < 128*67; gg += 256) {
    int o = gg / 67, c = gg - o*67;
    sh.W[o*69+c] = Wkern[gg];
  }
  __syncthreads();
  {
    int k = t >> 4, cg = t & 15;
    int idx = sh.sel[k];
    float4 f = *reinterpret_cast<const float4*>(ws + WS_PTS_T + ((size_t)b*NPT + idx)*ND + cg*4);
    float* nprow = sh.np + k*69;
    nprow[3+cg*4+0]=f.x; nprow[3+cg*4+1]=f.y; nprow[3+cg*4+2]=f.z; nprow[3+cg*4+3]=f.w;
    if (cg == 0) {
      float4 g4 = *reinterpret_cast<const float4*>(ws + WS_XYZW + ((size_t)b*NPT + idx)*4);
      nprow[0]=g4.x-q.x; nprow[1]=g4.y-q.y; nprow[2]=g4.z-q.z;
    }
  }
  __syncthreads();

  const int o = t & 127, khalf = t >> 7, k0 = khalf*8;
  float acc[8] = {0,0,0,0,0,0,0,0};
  const float* Wrow = sh.W + o*69;
  for (int c = 0; c < 67; c++) {
    float w = Wrow[c];
#pragma unroll
    for (int kk = 0; kk < 8; kk++)
      acc[kk] = fmaf(w, sh.np[(k0+kk)*69 + c], acc[kk]);
  }
  float pw = 0.f;
#pragma unroll
  for (int kk = 0; kk < 8; kk++) {
    float a = acc[kk]; a = (a >= 0.f) ? a : 0.1f*a;
    pw = fmaf(a, sh.g[128 + k0 + kk], pw);
  }
  sh.pr[khalf*128 + o] = pw;
  __syncthreads();
  if (t < 128) {
    float v = (sh.pr[t] + sh.pr[128+t]) * sh.g[t] * 0.0625f;
    dout[OUT_FEAT + ((size_t)b*NO + t)*NS + s] = v;
  }
}

extern "C" void kernel_launch(void* const* d_in, const int* in_sizes, int n_in,
                              void* d_out, int out_size, void* d_ws, size_t ws_size,
                              hipStream_t stream) {
  (void)in_sizes; (void)n_in; (void)out_size; (void)ws_size;
  const float* xyz    = (const float*)d_in[0];
  const float* points = (const float*)d_in[1];
  const float* Wk     = (const float*)d_in[2];
  const float* Wl     = (const float*)d_in[3];
  const float* Wp     = (const float*)d_in[4];
  const float* Wc     = (const float*)d_in[5];
  float* ws  = (float*)d_ws;
  float* out = (float*)d_out;

  hipLaunchKernelGGL(k_prep, dim3(NB + 1024 + 64), dim3(1024), 0, stream, xyz, points, ws, out);
  hipLaunchKernelGGL(k_knn_feat1, dim3(NB*NS), dim3(256), 0, stream, Wk, ws);
  hipLaunchKernelGGL(k_linear, dim3(NB*NS/8), dim3(256), 0, stream, Wl, Wp, Wc, ws);
  hipLaunchKernelGGL(k_final, dim3(NB*NS), dim3(256), 0, stream, Wk, ws, out);
}

// Round 2
// 3358.213 us; speedup vs baseline: 1.0842x; 1.0842x over previous
//
#include <hip/hip_runtime.h>
#include <stdint.h>

// Problem constants
#define NB 8
#define NPT 8192
#define ND 64
#define NO 128
#define NS 2048
#define NK 16

// Workspace layout (in floats)
constexpr int WS_PTS_T  = 0;                         // [B][N][64] transposed points
constexpr int WS_XYZW   = WS_PTS_T + NB*NPT*ND;      // [B][N][4] x,y,z,|p|^2
constexpr int WS_NEWXYZ = WS_XYZW + NB*NPT*4;        // [B][S][4] x,y,z,|q|^2
constexpr int WS_KNN    = WS_NEWXYZ + NB*NS*4;       // [B][S][16] int
constexpr int WS_AGG    = WS_KNN + NB*NS*NK;         // [B][S][144]
constexpr int WS_GATES  = WS_AGG + NB*NS*144;        // [B][S][144] (wc 0..127, wp 128..143)

// Output layout (floats): new_xyz [B][3][S], out [B][O][S], fps_idx [B][S]
constexpr int OUT_NEWXYZ = 0;
constexpr int OUT_FEAT   = NB*3*NS;
constexpr int OUT_FPS    = OUT_FEAT + NB*NO*NS;

__device__ __forceinline__ float sq3(float x, float y, float z) {
#pragma clang fp contract(off)
  return (x*x + y*y) + z*z;
}

__device__ __forceinline__ float fps_d(float px,float py,float pz,float cx,float cy,float cz) {
#pragma clang fp contract(off)
  float dx = px-cx, dy = py-cy, dz = pz-cz;
  return (dx*dx + dy*dy) + dz*dz;
}

__device__ __forceinline__ float knn_d(float qn, float pn,
                                       float qx,float qy,float qz,
                                       float px,float py,float pz) {
#pragma clang fp contract(off)
  float dot = (qx*px + qy*py) + qz*pz;
  return (qn + pn) - 2.0f*dot;
}

// ---------------- Kernel 1: fused FPS (blocks 0..7) + points transpose + xyzw build ----
struct FpsShared {
  float lx[NPT], ly[NPT], lz[NPT];
  unsigned long long wred[2][8];
};
struct TrShared { float tile[64][65]; };
union PrepShared { FpsShared f; TrShared t; };

__global__ __launch_bounds__(512) void k_prep(const float* __restrict__ xyz,
                                              const float* __restrict__ points,
                                              float* __restrict__ ws,
                                              float* __restrict__ dout) {
  __shared__ PrepShared sh;
  const int bid = blockIdx.x, t = threadIdx.x;

  if (bid < NB) {
    // ---- FPS for batch bid: 512 threads, thread t owns contiguous points [16t, 16t+16) ----
    const float* xb = xyz + (size_t)bid*3*NPT;
    float px[16], py[16], pz[16], dist[16];
    const int base = t << 4;
#pragma unroll
    for (int jj = 0; jj < 4; jj++) {
      float4 vx = *reinterpret_cast<const float4*>(xb + base + jj*4);
      float4 vy = *reinterpret_cast<const float4*>(xb + NPT + base + jj*4);
      float4 vz = *reinterpret_cast<const float4*>(xb + 2*NPT + base + jj*4);
      px[jj*4+0]=vx.x; px[jj*4+1]=vx.y; px[jj*4+2]=vx.z; px[jj*4+3]=vx.w;
      py[jj*4+0]=vy.x; py[jj*4+1]=vy.y; py[jj*4+2]=vy.z; py[jj*4+3]=vy.w;
      pz[jj*4+0]=vz.x; pz[jj*4+1]=vz.y; pz[jj*4+2]=vz.z; pz[jj*4+3]=vz.w;
#pragma unroll
      for (int i = 0; i < 4; i++) {
        int n = base + jj*4 + i;
        sh.f.lx[n]=px[jj*4+i]; sh.f.ly[n]=py[jj*4+i]; sh.f.lz[n]=pz[jj*4+i];
        dist[jj*4+i] = 1e10f;
      }
    }
    __syncthreads();

    int far = 0;
    float* nxw  = ws + WS_NEWXYZ + (size_t)bid*NS*4;
    float* nxo  = dout + OUT_NEWXYZ + (size_t)bid*3*NS;
    float* fpso = dout + OUT_FPS + (size_t)bid*NS;

    for (int s = 0; s < NS; s++) {
      float cx = sh.f.lx[far], cy = sh.f.ly[far], cz = sh.f.lz[far];
      if (t == 0) {
        fpso[s] = (float)far;
        nxo[s] = cx; nxo[NS+s] = cy; nxo[2*NS+s] = cz;
        float cw = sq3(cx, cy, cz);
        nxw[s*4+0]=cx; nxw[s*4+1]=cy; nxw[s*4+2]=cz; nxw[s*4+3]=cw;
      }
      // update running min distance + local argmax (first-index tie-break: ascending scan, strict >)
      float bv = -1.0f; int bi = base;
#pragma unroll
      for (int j = 0; j < 16; j++) {
        float d = fps_d(px[j], py[j], pz[j], cx, cy, cz);
        float nd = fminf(dist[j], d);
        dist[j] = nd;
        if (nd > bv) { bv = nd; bi = base + j; }
      }
      // wave max (value only, 32-bit)
      float wmax = bv;
#pragma unroll
      for (int m = 1; m < 64; m <<= 1)
        wmax = fmaxf(wmax, __shfl_xor(wmax, m, 64));
      // winner = lowest lane holding wmax -> its bi is the first (lowest-index) max in this wave
      unsigned long long eq = __ballot(bv == wmax);
      int winner = __ffsll(eq) - 1;
      int wbi = __shfl(bi, winner, 64);
      const int par = s & 1;
      if ((t & 63) == 0)
        sh.f.wred[par][t >> 6] = ((unsigned long long)__float_as_uint(wmax) << 32) | (unsigned)wbi;
      __syncthreads();
      // stage 2: 8 wave slots, ascending wave id = ascending point ranges; strict > keeps lowest index
      unsigned long long best = sh.f.wred[par][0];
#pragma unroll
      for (int w = 1; w < 8; w++) {
        unsigned long long k2 = sh.f.wred[par][w];
        if ((unsigned)(k2 >> 32) > (unsigned)(best >> 32)) best = k2;
      }
      far = (int)(best & 0xFFFFFFFFull);
    }
  } else if (bid < NB + 1024) {
    // ---- transpose points [B][64][N] -> pts_t [B][N][64], 64x64 tiles, 512 threads ----
    const int tb = bid - NB;
    const int b  = tb >> 7;            // 128 n-tiles per batch
    const int n0 = (tb & 127) << 6;
    const float* pb = points + (size_t)b*ND*NPT;
    {
      int dR = t >> 3, cg = t & 7;     // each thread: 8 floats of one d-row
      const float* src = pb + (size_t)dR*NPT + n0 + cg*8;
      float4 v0 = *reinterpret_cast<const float4*>(src);
      float4 v1 = *reinterpret_cast<const float4*>(src + 4);
      sh.t.tile[dR][cg*8+0]=v0.x; sh.t.tile[dR][cg*8+1]=v0.y;
      sh.t.tile[dR][cg*8+2]=v0.z; sh.t.tile[dR][cg*8+3]=v0.w;
      sh.t.tile[dR][cg*8+4]=v1.x; sh.t.tile[dR][cg*8+5]=v1.y;
      sh.t.tile[dR][cg*8+6]=v1.z; sh.t.tile[dR][cg*8+7]=v1.w;
    }
    __syncthreads();
    {
      int nl = t >> 3, dg = t & 7;
      float4 w0, w1;
      w0.x = sh.t.tile[dg*8+0][nl]; w0.y = sh.t.tile[dg*8+1][nl];
      w0.z = sh.t.tile[dg*8+2][nl]; w0.w = sh.t.tile[dg*8+3][nl];
      w1.x = sh.t.tile[dg*8+4][nl]; w1.y = sh.t.tile[dg*8+5][nl];
      w1.z = sh.t.tile[dg*8+6][nl]; w1.w = sh.t.tile[dg*8+7][nl];
      float* dst = ws + WS_PTS_T + ((size_t)b*NPT + n0 + nl)*ND + dg*8;
      *reinterpret_cast<float4*>(dst)     = w0;
      *reinterpret_cast<float4*>(dst + 4) = w1;
    }
  } else {
    // ---- xyzw build: [B][N][4] = x,y,z,|p|^2 ; 128 blocks * 512 threads = B*N ----
    int g = (bid - (NB + 1024))*512 + t;
    int b = g >> 13, n = g & 8191;
    const float* xb = xyz + (size_t)b*3*NPT;
    float x = xb[n], y = xb[NPT+n], z = xb[2*NPT+n];
    float4 v; v.x=x; v.y=y; v.z=z; v.w=sq3(x,y,z);
    *reinterpret_cast<float4*>(ws + WS_XYZW + (size_t)g*4) = v;
  }
}

// ---------------- Kernel 2: KNN + feat pass 1 (ch_avg / pt_avg -> agg) --------------
struct K2Shared {
  union {
    float dist[NPT];                       // 32 KB (phase A/B)
    struct {
      float W[128*69];                     // W_kernel staged, row stride 69 (odd->conflict-free)
      float np[16*69];                     // grouped features [k][67]
      float ft[16*132];                    // feat tile [k][o]
      float chred[256];
      float ptred[16*17];
    } p2;
  } u;
  unsigned long long kred[4];
  int selIdx[16];
};

__global__ __launch_bounds__(256) void k_knn_feat1(const float* __restrict__ Wkern,
                                                   float* __restrict__ ws) {
  __shared__ K2Shared sh;
  const int bid = blockIdx.x, t = threadIdx.x;
  const int b = bid >> 11, s = bid & 2047;
  const float* xyzw = ws + WS_XYZW + (size_t)b*NPT*4;
  const float4 q = *reinterpret_cast<const float4*>(ws + WS_NEWXYZ + ((size_t)b*NS + s)*4);

  // phase A: full distance row into LDS
  for (int i = 0; i < 32; i++) {
    int n = t + (i << 8);
    float4 p = *reinterpret_cast<const float4*>(xyzw + (size_t)n*4);
    sh.u.dist[n] = knn_d(q.w, p.w, q.x, q.y, q.z, p.x, p.y, p.z);
  }
  __syncthreads();

  // phase B: 16 x (argmin + mark) == stable top-16 (ties -> lower index)
  int* knn = (int*)(ws + WS_KNN) + ((size_t)b*NS + s)*NK;
  for (int r = 0; r < NK; r++) {
    float bv = __int_as_float(0x7F800000); int bi = NPT;
    for (int i = 0; i < 32; i++) {
      int n = t + (i << 8);
      float v = sh.u.dist[n];
      if (v < bv) { bv = v; bi = n; }
    }
    unsigned u = __float_as_uint(bv);
    u ^= ((unsigned)((int)u >> 31)) | 0x80000000u;   // order-preserving map (handles negatives)
    unsigned long long key = ((unsigned long long)u << 32) | (unsigned)bi;
#pragma unroll
    for (int m = 1; m < 64; m <<= 1) {
      unsigned long long o = __shfl_xor(key, m, 64);
      key = (o < key) ? o : key;
    }
    if ((t & 63) == 0) sh.kred[t >> 6] = key;
    __syncthreads();
    {
      unsigned long long kmin = sh.kred[0];
#pragma unroll
      for (int w = 1; w < 4; w++) { unsigned long long o = sh.kred[w]; kmin = (o < kmin) ? o : kmin; }
      int win = (int)(kmin & 0xFFFFFFFFull);
      if (t == 0) { sh.selIdx[r] = win; knn[r] = win; sh.u.dist[win] = __int_as_float(0x7F800000); }
    }
    __syncthreads();
  }

  // phase C: gather grouped features into LDS (np[k][0..2]=gxyz-q, [3..66]=pts_t row)
  {
    int k = t >> 4, cg = t & 15;
    int idx = sh.selIdx[k];
    float4 f = *reinterpret_cast<const float4*>(ws + WS_PTS_T + ((size_t)b*NPT + idx)*ND + cg*4);
    float* nprow = sh.u.p2.np + k*69;
    nprow[3+cg*4+0]=f.x; nprow[3+cg*4+1]=f.y; nprow[3+cg*4+2]=f.z; nprow[3+cg*4+3]=f.w;
    if (cg == 0) {
      float4 g4 = *reinterpret_cast<const float4*>(xyzw + (size_t)idx*4);
      nprow[0]=g4.x-q.x; nprow[1]=g4.y-q.y; nprow[2]=g4.z-q.z;
    }
  }
  // stage W_kernel
  for (int g = t; g < 128*67; g += 256) {
    int o = g / 67, c = g - o*67;
    sh.u.p2.W[o*69+c] = Wkern[g];
  }
  __syncthreads();

  // phase E: feat[o][k] = leaky(W . np)
  const int o = t & 127, khalf = t >> 7, k0 = khalf*8;
  float acc[8] = {0,0,0,0,0,0,0,0};
  const float* Wrow = sh.u.p2.W + o*69;
  for (int c = 0; c < 67; c++) {
    float w = Wrow[c];
#pragma unroll
    for (int kk = 0; kk < 8; kk++)
      acc[kk] = fmaf(w, sh.u.p2.np[(k0+kk)*69 + c], acc[kk]);
  }
#pragma unroll
  for (int kk = 0; kk < 8; kk++) { float a = acc[kk]; acc[kk] = (a >= 0.f) ? a : 0.1f*a; }

  // phase F: ch_avg + pt_avg -> agg[b][s][144]
  float chp = 0.f;
#pragma unroll
  for (int kk = 0; kk < 8; kk++) { sh.u.p2.ft[(k0+kk)*132 + o] = acc[kk]; chp += acc[kk]; }
  sh.u.p2.chred[khalf*128 + o] = chp;
  __syncthreads();
  float* agg = ws + WS_AGG + ((size_t)b*NS + s)*144;
  if (t < 128) agg[t] = (sh.u.p2.chred[t] + sh.u.p2.chred[128+t]) * 0.0625f;
  {
    int k = t & 15, og = t >> 4;
    float pp = 0.f;
#pragma unroll
    for (int j = 0; j < 8; j++) pp += sh.u.p2.ft[k*132 + og*8 + j];
    sh.u.p2.ptred[k*17 + og] = pp;
  }
  __syncthreads();
  if (t < 16) {
    float pv = 0.f;
#pragma unroll
    for (int og = 0; og < 16; og++) pv += sh.u.p2.ptred[t*17 + og];
    agg[128 + t] = pv * 0.0078125f;
  }
}

// ---------------- Kernel 3: linear + gates ----------------
struct K3Shared {
  float Wlin[144*145];
  float Wch[128*129];
  float Wpt[16*17];
  float av[144];
  float a2[144];
};

__global__ __launch_bounds__(256) void k_linear(const float* __restrict__ Wlin,
                                                const float* __restrict__ Wpt,
                                                const float* __restrict__ Wch,
                                                float* __restrict__ ws) {
  __shared__ K3Shared sh;
  const int t = threadIdx.x, bid = blockIdx.x;
  for (int g = t; g < 144*144; g += 256) { int o = g/144, c = g - o*144; sh.Wlin[o*145+c] = Wlin[g]; }
  for (int g = t; g < 128*128; g += 256) { int o = g>>7, c = g&127;      sh.Wch[o*129+c]  = Wch[g]; }
  if (t < 256) { int o = t>>4, c = t&15; sh.Wpt[o*17+c] = Wpt[t]; }
  __syncthreads();

  for (int i = 0; i < 8; i++) {
    const size_t sg = (size_t)bid*8 + i;
    const float* agg = ws + WS_AGG + sg*144;
    if (t < 144) sh.av[t] = agg[t];
    __syncthreads();
    if (t < 144) {
      float a = 0.f;
      const float* wr = sh.Wlin + t*145;
      for (int c = 0; c < 144; c++) a = fmaf(wr[c], sh.av[c], a);
      sh.a2[t] = (a >= 0.f) ? a : 0.1f*a;
    }
    __syncthreads();
    float* gates = ws + WS_GATES + sg*144;
    if (t < 128) {
      float a = 0.f;
      const float* wr = sh.Wch + t*129;
      for (int c = 0; c < 128; c++) a = fmaf(wr[c], sh.a2[c], a);
      gates[t] = 1.f / (1.f + expf(-a));
    } else if (t < 144) {
      int o = t - 128;
      float a = 0.f;
      const float* wr = sh.Wpt + o*17;
      for (int c = 0; c < 16; c++) a = fmaf(wr[c], sh.a2[128+c], a);
      gates[t] = 1.f / (1.f + expf(-a));
    }
    __syncthreads();
  }
}

// ---------------- Kernel 4: recompute feat, gate, mean over k -> out ----------------
struct K4Shared {
  float W[128*69];
  float np[16*69];
  float pr[256];
  float g[144];
  int sel[16];
};

__global__ __launch_bounds__(256) void k_final(const float* __restrict__ Wkern,
                                               const float* __restrict__ ws,
                                               float* __restrict__ dout) {
  __shared__ K4Shared sh;
  const int bid = blockIdx.x, t = threadIdx.x;
  const int b = bid >> 11, s = bid & 2047;
  const int* knn = (const int*)(ws + WS_KNN) + ((size_t)b*NS + s)*NK;
  if (t < 16)  sh.sel[t] = knn[t];
  if (t < 144) sh.g[t] = ws[WS_GATES + ((size_t)b*NS + s)*144 + t];
  const float4 q = *reinterpret_cast<const float4*>(ws + WS_NEWXYZ + ((size_t)b*NS + s)*4);
  for (int gg = t; gg < 128*67; gg += 256) {
    int o = gg / 67, c = gg - o*67;
    sh.W[o*69+c] = Wkern[gg];
  }
  __syncthreads();
  {
    int k = t >> 4, cg = t & 15;
    int idx = sh.sel[k];
    float4 f = *reinterpret_cast<const float4*>(ws + WS_PTS_T + ((size_t)b*NPT + idx)*ND + cg*4);
    float* nprow = sh.np + k*69;
    nprow[3+cg*4+0]=f.x; nprow[3+cg*4+1]=f.y; nprow[3+cg*4+2]=f.z; nprow[3+cg*4+3]=f.w;
    if (cg == 0) {
      float4 g4 = *reinterpret_cast<const float4*>(ws + WS_XYZW + ((size_t)b*NPT + idx)*4);
      nprow[0]=g4.x-q.x; nprow[1]=g4.y-q.y; nprow[2]=g4.z-q.z;
    }
  }
  __syncthreads();

  const int o = t & 127, khalf = t >> 7, k0 = khalf*8;
  float acc[8] = {0,0,0,0,0,0,0,0};
  const float* Wrow = sh.W + o*69;
  for (int c = 0; c < 67; c++) {
    float w = Wrow[c];
#pragma unroll
    for (int kk = 0; kk < 8; kk++)
      acc[kk] = fmaf(w, sh.np[(k0+kk)*69 + c], acc[kk]);
  }
  float pw = 0.f;
#pragma unroll
  for (int kk = 0; kk < 8; kk++) {
    float a = acc[kk]; a = (a >= 0.f) ? a : 0.1f*a;
    pw = fmaf(a, sh.g[128 + k0 + kk], pw);
  }
  sh.pr[khalf*128 + o] = pw;
  __syncthreads();
  if (t < 128) {
    float v = (sh.pr[t] + sh.pr[128+t]) * sh.g[t] * 0.0625f;
    dout[OUT_FEAT + ((size_t)b*NO + t)*NS + s] = v;
  }
}

extern "C" void kernel_launch(void* const* d_in, const int* in_sizes, int n_in,
                              void* d_out, int out_size, void* d_ws, size_t ws_size,
                              hipStream_t stream) {
  (void)in_sizes; (void)n_in; (void)out_size; (void)ws_size;
  const float* xyz    = (const float*)d_in[0];
  const float* points = (const float*)d_in[1];
  const float* Wk     = (const float*)d_in[2];
  const float* Wl     = (const float*)d_in[3];
  const float* Wp     = (const float*)d_in[4];
  const float* Wc     = (const float*)d_in[5];
  float* ws  = (float*)d_ws;
  float* out = (float*)d_out;

  hipLaunchKernelGGL(k_prep, dim3(NB + 1024 + 128), dim3(512), 0, stream, xyz, points, ws, out);
  hipLaunchKernelGGL(k_knn_feat1, dim3(NB*NS), dim3(256), 0, stream, Wk, ws);
  hipLaunchKernelGGL(k_linear, dim3(NB*NS/8), dim3(256), 0, stream, Wl, Wp, Wc, ws);
  hipLaunchKernelGGL(k_final, dim3(NB*NS), dim3(256), 0, stream, Wk, ws, out);
}

// Round 3
// 2469.646 us; speedup vs baseline: 1.4743x; 1.3598x over previous
//
#include <hip/hip_runtime.h>
#include <stdint.h>

// Problem constants
#define NB 8
#define NPT 8192
#define ND 64
#define NO 128
#define NS 2048
#define NK 16
#define NCONS 248   // consumer blocks
#define NITER 67    // ceil(B*S / NCONS) = ceil(16384/248)

// Workspace layout (in floats)
constexpr int WS_PTS_T  = 0;                         // [B][N][64] transposed points
constexpr int WS_XYZW   = WS_PTS_T + NB*NPT*ND;      // [B][N][4] x,y,z,|p|^2
constexpr int WS_NEWXYZ = WS_XYZW + NB*NPT*4;        // [B][S][4] x,y,z,|q|^2
constexpr int WS_SYNC   = WS_NEWXYZ + NB*NS*4;       // int[16]: progress[8], prep_done

// Output layout (floats): new_xyz [B][3][S], out [B][O][S], fps_idx [B][S]
constexpr int OUT_NEWXYZ = 0;
constexpr int OUT_FEAT   = NB*3*NS;
constexpr int OUT_FPS    = OUT_FEAT + NB*NO*NS;

__device__ __forceinline__ float sq3(float x, float y, float z) {
#pragma clang fp contract(off)
  return (x*x + y*y) + z*z;
}

__device__ __forceinline__ float fps_d(float px,float py,float pz,float cx,float cy,float cz) {
#pragma clang fp contract(off)
  float dx = px-cx, dy = py-cy, dz = pz-cz;
  return (dx*dx + dy*dy) + dz*dz;
}

__device__ __forceinline__ float knn_d(float qn, float pn,
                                       float qx,float qy,float qz,
                                       float px,float py,float pz) {
#pragma clang fp contract(off)
  float dot = (qx*px + qy*py) + qz*pz;
  return (qn + pn) - 2.0f*dot;
}

__global__ void k_init(float* __restrict__ ws) {
  if (threadIdx.x < 16) ((int*)(ws + WS_SYNC))[threadIdx.x] = 0;
}

struct MegaShared {
  union {
    struct {                                  // FPS producer (~98.4 KB)
      float lx[NPT], ly[NPT], lz[NPT];
      unsigned long long wred[2][8];
    } f;
    struct { float tile[64][65]; } tr;        // prep transpose
    struct {                                  // consumer (~70 KB)
      float W[128*69];                        // W_kernel, stride 69
      union {
        float dist[NPT];                      // 32 KB
        struct { float np[16*69]; float ft[16*132]; float chred[256]; float ptred[16*17]; } p2;
      } u;
      unsigned long long kred[8];
      int selIdx[16];
      float agg[144];
      float a2[144];
      float gates[144];
    } c;
  } u;
};

__global__ __launch_bounds__(512) void k_mega(const float* __restrict__ xyz,
                                              const float* __restrict__ points,
                                              const float* __restrict__ Wkern,
                                              const float* __restrict__ Wlin,
                                              const float* __restrict__ Wpt,
                                              const float* __restrict__ Wch,
                                              float* __restrict__ ws,
                                              float* __restrict__ dout) {
  __shared__ MegaShared sh;
  const int bid = blockIdx.x, t = threadIdx.x;
  int* syncp = (int*)(ws + WS_SYNC);

  if (bid < NB) {
    // ================= FPS producer (identical inner loop to validated R2) =============
    const float* xb = xyz + (size_t)bid*3*NPT;
    float px[16], py[16], pz[16], dist[16];
    const int base = t << 4;
#pragma unroll
    for (int jj = 0; jj < 4; jj++) {
      float4 vx = *reinterpret_cast<const float4*>(xb + base + jj*4);
      float4 vy = *reinterpret_cast<const float4*>(xb + NPT + base + jj*4);
      float4 vz = *reinterpret_cast<const float4*>(xb + 2*NPT + base + jj*4);
      px[jj*4+0]=vx.x; px[jj*4+1]=vx.y; px[jj*4+2]=vx.z; px[jj*4+3]=vx.w;
      py[jj*4+0]=vy.x; py[jj*4+1]=vy.y; py[jj*4+2]=vy.z; py[jj*4+3]=vy.w;
      pz[jj*4+0]=vz.x; pz[jj*4+1]=vz.y; pz[jj*4+2]=vz.z; pz[jj*4+3]=vz.w;
#pragma unroll
      for (int i = 0; i < 4; i++) {
        int n = base + jj*4 + i;
        sh.u.f.lx[n]=px[jj*4+i]; sh.u.f.ly[n]=py[jj*4+i]; sh.u.f.lz[n]=pz[jj*4+i];
        dist[jj*4+i] = 1e10f;
      }
    }
    __syncthreads();

    int far = 0;
    float* nxw  = ws + WS_NEWXYZ + (size_t)bid*NS*4;
    float* nxo  = dout + OUT_NEWXYZ + (size_t)bid*3*NS;
    float* fpso = dout + OUT_FPS + (size_t)bid*NS;

    for (int s = 0; s < NS; s++) {
      float cx = sh.u.f.lx[far], cy = sh.u.f.ly[far], cz = sh.u.f.lz[far];
      if (t == 0) {
        fpso[s] = (float)far;
        nxo[s] = cx; nxo[NS+s] = cy; nxo[2*NS+s] = cz;
        float cw = sq3(cx, cy, cz);
        nxw[s*4+0]=cx; nxw[s*4+1]=cy; nxw[s*4+2]=cz; nxw[s*4+3]=cw;
        if ((s & 7) == 7)  // publish centers [0..s] (release: prior stores reach IF$ first)
          __hip_atomic_store(&syncp[bid], s+1, __ATOMIC_RELEASE, __HIP_MEMORY_SCOPE_AGENT);
      }
      float bv = -1.0f; int bi = base;
#pragma unroll
      for (int j = 0; j < 16; j++) {
        float d = fps_d(px[j], py[j], pz[j], cx, cy, cz);
        float nd = fminf(dist[j], d);
        dist[j] = nd;
        if (nd > bv) { bv = nd; bi = base + j; }
      }
      float wmax = bv;
#pragma unroll
      for (int m = 1; m < 64; m <<= 1)
        wmax = fmaxf(wmax, __shfl_xor(wmax, m, 64));
      unsigned long long eq = __ballot(bv == wmax);
      int winner = __ffsll(eq) - 1;
      int wbi = __shfl(bi, winner, 64);
      const int par = s & 1;
      if ((t & 63) == 0)
        sh.u.f.wred[par][t >> 6] = ((unsigned long long)__float_as_uint(wmax) << 32) | (unsigned)wbi;
      __syncthreads();
      unsigned long long best = sh.u.f.wred[par][0];
#pragma unroll
      for (int w = 1; w < 8; w++) {
        unsigned long long k2 = sh.u.f.wred[par][w];
        if ((unsigned)(k2 >> 32) > (unsigned)(best >> 32)) best = k2;
      }
      far = (int)(best & 0xFFFFFFFFull);
    }
    if (t == 0)  // final publish (s=2047 covered by (s&7)==7, but be explicit)
      __hip_atomic_store(&syncp[bid], NS, __ATOMIC_RELEASE, __HIP_MEMORY_SCOPE_AGENT);
    return;
  }

  // ================= Consumer block =================
  const int cbid = bid - NB;   // 0..247

  // ---- prep phase: transpose points -> pts_t ----
  for (int tile = cbid; tile < 1024; tile += NCONS) {
    const int b  = tile >> 7;
    const int n0 = (tile & 127) << 6;
    const float* pb = points + (size_t)b*ND*NPT;
    {
      int dR = t >> 3, cg = t & 7;
      const float* src = pb + (size_t)dR*NPT + n0 + cg*8;
      float4 v0 = *reinterpret_cast<const float4*>(src);
      float4 v1 = *reinterpret_cast<const float4*>(src + 4);
      sh.u.tr.tile[dR][cg*8+0]=v0.x; sh.u.tr.tile[dR][cg*8+1]=v0.y;
      sh.u.tr.tile[dR][cg*8+2]=v0.z; sh.u.tr.tile[dR][cg*8+3]=v0.w;
      sh.u.tr.tile[dR][cg*8+4]=v1.x; sh.u.tr.tile[dR][cg*8+5]=v1.y;
      sh.u.tr.tile[dR][cg*8+6]=v1.z; sh.u.tr.tile[dR][cg*8+7]=v1.w;
    }
    __syncthreads();
    {
      int nl = t >> 3, dg = t & 7;
      float4 w0, w1;
      w0.x = sh.u.tr.tile[dg*8+0][nl]; w0.y = sh.u.tr.tile[dg*8+1][nl];
      w0.z = sh.u.tr.tile[dg*8+2][nl]; w0.w = sh.u.tr.tile[dg*8+3][nl];
      w1.x = sh.u.tr.tile[dg*8+4][nl]; w1.y = sh.u.tr.tile[dg*8+5][nl];
      w1.z = sh.u.tr.tile[dg*8+6][nl]; w1.w = sh.u.tr.tile[dg*8+7][nl];
      float* dst = ws + WS_PTS_T + ((size_t)b*NPT + n0 + nl)*ND + dg*8;
      *reinterpret_cast<float4*>(dst)     = w0;
      *reinterpret_cast<float4*>(dst + 4) = w1;
    }
    __syncthreads();
  }
  // ---- prep phase: xyzw ----
  for (int chunk = cbid; chunk < 128; chunk += NCONS) {
    int g = chunk*512 + t;
    int b = g >> 13, n = g & 8191;
    const float* xb = xyz + (size_t)b*3*NPT;
    float x = xb[n], y = xb[NPT+n], z = xb[2*NPT+n];
    float4 v; v.x=x; v.y=y; v.z=z; v.w=sq3(x,y,z);
    *reinterpret_cast<float4*>(ws + WS_XYZW + (size_t)g*4) = v;
  }
  __syncthreads();
  if (t == 0) {
    __hip_atomic_fetch_add(&syncp[8], 1, __ATOMIC_ACQ_REL, __HIP_MEMORY_SCOPE_AGENT);
    while (__hip_atomic_load(&syncp[8], __ATOMIC_RELAXED, __HIP_MEMORY_SCOPE_AGENT) < NCONS)
      __builtin_amdgcn_s_sleep(8);
    (void)__hip_atomic_load(&syncp[8], __ATOMIC_ACQUIRE, __HIP_MEMORY_SCOPE_AGENT);
  }
  __syncthreads();

  // ---- stage W_kernel once (read-only thereafter) ----
  for (int g = t; g < 128*67; g += 512) {
    int o = g / 67, c = g - o*67;
    sh.u.c.W[o*69+c] = Wkern[g];
  }
  __syncthreads();

  // ---- center loop: uniform trip count, block-uniform active flag ----
  for (int j = 0; j < NITER; j++) {
    const int i = cbid + j*NCONS;
    const bool active = (i < NB*NS);
    const int ii = active ? i : (NB*NS - 1);
    const int b = ii & 7, s = ii >> 3;

    if (t == 0) {
      while (__hip_atomic_load(&syncp[b], __ATOMIC_RELAXED, __HIP_MEMORY_SCOPE_AGENT) < s+1)
        __builtin_amdgcn_s_sleep(8);
      (void)__hip_atomic_load(&syncp[b], __ATOMIC_ACQUIRE, __HIP_MEMORY_SCOPE_AGENT);
    }
    __syncthreads();

    const float* xyzw = ws + WS_XYZW + (size_t)b*NPT*4;
    const float4 q = *reinterpret_cast<const float4*>(ws + WS_NEWXYZ + ((size_t)b*NS + s)*4);

    // phase A: distance row
#pragma unroll
    for (int i2 = 0; i2 < 16; i2++) {
      int n = t + (i2 << 9);
      float4 p = *reinterpret_cast<const float4*>(xyzw + (size_t)n*4);
      sh.u.c.u.dist[n] = knn_d(q.w, p.w, q.x, q.y, q.z, p.x, p.y, p.z);
    }
    __syncthreads();

    // phase B: stable top-16 (argmin + mark)
    for (int r = 0; r < NK; r++) {
      float bv = __int_as_float(0x7F800000); int bi = NPT;
#pragma unroll
      for (int i2 = 0; i2 < 16; i2++) {
        int n = t + (i2 << 9);
        float v = sh.u.c.u.dist[n];
        if (v < bv) { bv = v; bi = n; }
      }
      unsigned uu = __float_as_uint(bv);
      uu ^= ((unsigned)((int)uu >> 31)) | 0x80000000u;
      unsigned long long key = ((unsigned long long)uu << 32) | (unsigned)bi;
#pragma unroll
      for (int m = 1; m < 64; m <<= 1) {
        unsigned long long o = __shfl_xor(key, m, 64);
        key = (o < key) ? o : key;
      }
      if ((t & 63) == 0) sh.u.c.kred[t >> 6] = key;
      __syncthreads();
      if (t == 0) {
        unsigned long long kmin = sh.u.c.kred[0];
#pragma unroll
        for (int w = 1; w < 8; w++) { unsigned long long o = sh.u.c.kred[w]; if (o < kmin) kmin = o; }
        int win = (int)(kmin & 0xFFFFFFFFull);
        sh.u.c.selIdx[r] = win;
        sh.u.c.u.dist[win] = __int_as_float(0x7F800000);
      }
      __syncthreads();
    }

    // phase C: gather grouped features (t<256)
    if (t < 256) {
      int k = t >> 4, cg = t & 15;
      int idx = sh.u.c.selIdx[k];
      float4 f = *reinterpret_cast<const float4*>(ws + WS_PTS_T + ((size_t)b*NPT + idx)*ND + cg*4);
      float* nprow = sh.u.c.u.p2.np + k*69;
      nprow[3+cg*4+0]=f.x; nprow[3+cg*4+1]=f.y; nprow[3+cg*4+2]=f.z; nprow[3+cg*4+3]=f.w;
      if (cg == 0) {
        float4 g4 = *reinterpret_cast<const float4*>(xyzw + (size_t)idx*4);
        nprow[0]=g4.x-q.x; nprow[1]=g4.y-q.y; nprow[2]=g4.z-q.z;
      }
    }
    __syncthreads();

    // phase E: feat[o][k] = leaky(W . np)  (t<256)
    if (t < 256) {
      const int o = t & 127, khalf = t >> 7, k0 = khalf*8;
      float acc[8] = {0,0,0,0,0,0,0,0};
      const float* Wrow = sh.u.c.W + o*69;
      for (int c = 0; c < 67; c++) {
        float w = Wrow[c];
#pragma unroll
        for (int kk = 0; kk < 8; kk++)
          acc[kk] = fmaf(w, sh.u.c.u.p2.np[(k0+kk)*69 + c], acc[kk]);
      }
      float chp = 0.f;
#pragma unroll
      for (int kk = 0; kk < 8; kk++) {
        float a = acc[kk]; a = (a >= 0.f) ? a : 0.1f*a;
        sh.u.c.u.p2.ft[(k0+kk)*132 + o] = a; chp += a;
      }
      sh.u.c.u.p2.chred[khalf*128 + o] = chp;
    }
    __syncthreads();

    // phase F: ch_avg + pt_avg -> agg[144] in LDS
    if (t < 128) sh.u.c.agg[t] = (sh.u.c.u.p2.chred[t] + sh.u.c.u.p2.chred[128+t]) * 0.0625f;
    if (t < 256) {
      int k = t & 15, og = t >> 4;
      float pp = 0.f;
#pragma unroll
      for (int jj = 0; jj < 8; jj++) pp += sh.u.c.u.p2.ft[k*132 + og*8 + jj];
      sh.u.c.u.p2.ptred[k*17 + og] = pp;
    }
    __syncthreads();
    if (t < 16) {
      float pv = 0.f;
#pragma unroll
      for (int og = 0; og < 16; og++) pv += sh.u.c.u.p2.ptred[t*17 + og];
      sh.u.c.agg[128 + t] = pv * 0.0078125f;
    }
    __syncthreads();

    // linear: a2 = leaky(Wlin @ agg)   (weights from L1/L2; values identical to staged version)
    if (t < 144) {
      float a = 0.f;
      const float* wr = Wlin + t*144;
      for (int c = 0; c < 144; c++) a = fmaf(wr[c], sh.u.c.agg[c], a);
      sh.u.c.a2[t] = (a >= 0.f) ? a : 0.1f*a;
    }
    __syncthreads();

    // gates: wc = sigmoid(Wch @ a2[:128]), wp = sigmoid(Wpt @ a2[128:])
    if (t < 128) {
      float a = 0.f;
      const float* wr = Wch + t*128;
      for (int c = 0; c < 128; c++) a = fmaf(wr[c], sh.u.c.a2[c], a);
      sh.u.c.gates[t] = 1.f / (1.f + expf(-a));
    } else if (t < 144) {
      int o = t - 128;
      float a = 0.f;
      const float* wr = Wpt + o*16;
      for (int c = 0; c < 16; c++) a = fmaf(wr[c], sh.u.c.a2[128+c], a);
      sh.u.c.gates[t] = 1.f / (1.f + expf(-a));
    }
    __syncthreads();

    // final: gated mean over k straight from ft (no recompute)
    if (t < 128 && active) {
      float sum = 0.f;
#pragma unroll
      for (int k = 0; k < 16; k++)
        sum = fmaf(sh.u.c.u.p2.ft[k*132 + t], sh.u.c.gates[128 + k], sum);
      dout[OUT_FEAT + ((size_t)b*NO + t)*NS + s] = sum * sh.u.c.gates[t] * 0.0625f;
    }
    __syncthreads();   // protect ft/dist union + agg before next center
  }
}

extern "C" void kernel_launch(void* const* d_in, const int* in_sizes, int n_in,
                              void* d_out, int out_size, void* d_ws, size_t ws_size,
                              hipStream_t stream) {
  (void)in_sizes; (void)n_in; (void)out_size; (void)ws_size;
  const float* xyz    = (const float*)d_in[0];
  const float* points = (const float*)d_in[1];
  const float* Wk     = (const float*)d_in[2];
  const float* Wl     = (const float*)d_in[3];
  const float* Wp     = (const float*)d_in[4];
  const float* Wc     = (const float*)d_in[5];
  float* ws  = (float*)d_ws;
  float* out = (float*)d_out;

  hipLaunchKernelGGL(k_init, dim3(1), dim3(64), 0, stream, ws);

  void* args[] = { (void*)&xyz, (void*)&points, (void*)&Wk, (void*)&Wl,
                   (void*)&Wp, (void*)&Wc, (void*)&ws, (void*)&out };
  hipLaunchCooperativeKernel(reinterpret_cast<void*>(k_mega),
                             dim3(NB + NCONS), dim3(512), args, 0, stream);
}